// Round 6
// baseline (703.836 us; speedup 1.0000x reference)
//
#include <hip/hip_runtime.h>

// ROI adaptive average pooling — R8: 4-PASS VISIBILITY PROBE (not an optimization).
// B=8, C=1024, HW=14, N=512, FS=14, SCALE=1/16.
//
// Goal: surface the pool kernel in the rocprof top-5 (it has always been
// hidden below five ~262us fill dispatches) and measure its true HBM write
// throughput. R7's doubled-store probe was flawed: same-wave same-address
// rewrites were merged in L2 (zero extra HBM traffic, +6.5us).
//
// Method: REP=4 passes; pass r of block (n0,cg) processes ROI
// n_r=(n0+205r) mod 512 (bijection per pass -> full 411 MB coverage each
// pass). Each pass re-stages planes, recomputes geometry, gathers, stores
// CORRECT values to n_r's region. Every output location is written 4x by 4
// different blocks at times >> L2 dirty lifetime, byte-identical data ->
// correct under any order; each pass pays genuine HBM writes.
// Total W ~= 1.64 GB == the fill's WRITE_SIZE (same-workload comparator:
// fill does 1.64 GB in ~262us = 6.2 TB/s).
// Readout (pre-committed): D~=280-330 -> kernel at write floor -> revert+
// ROOFLINE. D~=550-650 -> ~2.7 TB/s store cap; FETCH~=W -> write-allocate
// RMW; FETCH small -> read VALUBusy/Occupancy.

#define FS_      14
#define PER_CH   196               // 14*14
#define C_       1024
#define CPB      32                // channels per block
#define QPC      49                // quads per channel (196/4)
#define NSTAGE4  (CPB * PER_CH / 4)  // 1568 float4 to stage
#define ACT      245               // active compute threads = 5*49
#define REP      4
#define ROTS     205u              // odd -> bijection mod 512

typedef float vfloat4 __attribute__((ext_vector_type(4)));

#if defined(__has_builtin)
# if __has_builtin(__builtin_amdgcn_global_load_lds)
#  define USE_GLL 1
# endif
# if __has_builtin(__builtin_nontemporal_store)
#  define USE_NT 1
# endif
#endif

static __device__ __forceinline__ void store_out(vfloat4 v, vfloat4* p) {
#if defined(USE_NT)
    __builtin_nontemporal_store(v, p);
#else
    *p = v;
#endif
}

__global__ __launch_bounds__(256) void roi_pool_kernel(
    const float* __restrict__ tensor,
    const float* __restrict__ roi,
    float* __restrict__ out)
{
    __shared__ float s_plane[CPB * PER_CH + 4];   // 25,104 B (+4 zeroed pad)
    __shared__ alignas(16) int   s_o00[PER_CH], s_o10[PER_CH];  // byte offsets
    __shared__ alignas(16) float s_mw[PER_CH], s_mh[PER_CH], s_inv[PER_CH];

    const unsigned bx = blockIdx.x;
    const unsigned n0 = bx >> 5;            // base ROI index
    const unsigned c0 = (bx & 31u) * CPB;   // first channel of this block

    const unsigned tid = threadIdx.x;

    // Zero the overread pad ONCE (staging writes bytes [0,25088) only).
    if (tid < 4u) s_plane[CPB * PER_CH + tid] = 0.0f;

    for (unsigned rep = 0; rep < REP; ++rep) {
        const unsigned n = (n0 + rep * ROTS) & 511u;   // this pass's ROI

        // ROI row [batch_idx, x1, y1, x2, y2] (uniform -> scalar).
        const float* r = roi + (size_t)n * 5;
        const int fm = (int)r[0];
        const int x1 = max((int)floorf(r[1] * 0.0625f), 0);
        const int y1 = max((int)floorf(r[2] * 0.0625f), 0);
        const int x2 = min((int)ceilf(r[3] * 0.0625f), FS_);
        const int y2 = min((int)ceilf(r[4] * 0.0625f), FS_);
        const unsigned Lh = (unsigned)(x2 - x1);   // 1..14 guaranteed
        const unsigned Lw = (unsigned)(y2 - y1);

        // Make sure the previous pass's gathers are done before overwriting
        // s_plane / geometry tables.
        __syncthreads();

        // ---- Geometry tables for ROI n (196 positions).
        if (tid < PER_CH) {
            const unsigned p = tid;
            const unsigned i = p / 14u;
            const unsigned j = p - i * 14u;
            const unsigned h0 = (i * Lh) / 14u;
            const unsigned h1 = ((i + 1u) * Lh + 13u) / 14u;
            const unsigned w0 = (j * Lw) / 14u;
            const unsigned w1 = ((j + 1u) * Lw + 13u) / 14u;
            const int dh = (int)(h1 - h0) - 1;     // 0 or 1
            const int dw = (int)(w1 - w0) - 1;     // 0 or 1
            const int a00 = (x1 + (int)h0) * FS_ + (y1 + (int)w0);
            s_o00[p] = a00 * 4;
            s_o10[p] = (a00 + FS_ * dh) * 4;
            s_mw[p]  = (float)dw;
            s_mh[p]  = (float)dh;
            const int cnt = (dh + 1) * (dw + 1);   // 1, 2, or 4
            s_inv[p] = (cnt == 1) ? 1.0f : ((cnt == 2) ? 0.5f : 0.25f);
        }

        // ---- Stage the 32 contiguous input planes of batch fm.
        const float4* __restrict__ src4 =
            (const float4*)(tensor + ((size_t)fm * C_ + c0) * PER_CH);
        float4* __restrict__ dst4 = (float4*)s_plane;
#pragma unroll
        for (unsigned k = 0; k < 7; ++k) {
            unsigned fi = k * 256u + tid;
            if (fi < NSTAGE4) {
#if defined(USE_GLL)
                __builtin_amdgcn_global_load_lds(
                    (const __attribute__((address_space(1))) void*)(src4 + fi),
                    (__attribute__((address_space(3))) void*)(dst4 + fi),
                    16, 0, 0);
#else
                dst4[fi] = src4[fi];
#endif
            }
        }

        __syncthreads();   // staging + geometry visible

        // ---- Gather + nt store for ROI n (245 active threads).
        if (tid < ACT) {
            const unsigned tc = tid / QPC;         // 0..4
            const unsigned q  = tid - tc * QPC;

            const int4   O00 = ((const int4*)s_o00)[q];
            const int4   O10 = ((const int4*)s_o10)[q];
            const float4 MW  = ((const float4*)s_mw)[q];
            const float4 MH  = ((const float4*)s_mh)[q];
            const float4 INV = ((const float4*)s_inv)[q];

            vfloat4* __restrict__ out4 =
                (vfloat4*)(out + ((size_t)n * C_ + c0) * PER_CH);

#pragma unroll
            for (unsigned it = 0; it < 7; ++it) {
                const unsigned cl = it * 5u + tc;  // local channel
                if (cl >= CPB) continue;           // trims last iteration
                const char* pb = (const char*)s_plane + cl * (PER_CH * 4);

                vfloat4 o;
                {
                    const char* p0 = pb + O00.x;
                    const char* p1 = pb + O10.x;
                    const float v00 = *(const float*)(p0);
                    const float v01 = *(const float*)(p0 + 4);  // ds_read2_b32
                    const float v10 = *(const float*)(p1);
                    const float v11 = *(const float*)(p1 + 4);
                    o.x = (fmaf(MW.x, v01, v00) + MH.x * fmaf(MW.x, v11, v10)) * INV.x;
                }
                {
                    const char* p0 = pb + O00.y;
                    const char* p1 = pb + O10.y;
                    const float v00 = *(const float*)(p0);
                    const float v01 = *(const float*)(p0 + 4);
                    const float v10 = *(const float*)(p1);
                    const float v11 = *(const float*)(p1 + 4);
                    o.y = (fmaf(MW.y, v01, v00) + MH.y * fmaf(MW.y, v11, v10)) * INV.y;
                }
                {
                    const char* p0 = pb + O00.z;
                    const char* p1 = pb + O10.z;
                    const float v00 = *(const float*)(p0);
                    const float v01 = *(const float*)(p0 + 4);
                    const float v10 = *(const float*)(p1);
                    const float v11 = *(const float*)(p1 + 4);
                    o.z = (fmaf(MW.z, v01, v00) + MH.z * fmaf(MW.z, v11, v10)) * INV.z;
                }
                {
                    const char* p0 = pb + O00.w;
                    const char* p1 = pb + O10.w;
                    const float v00 = *(const float*)(p0);
                    const float v01 = *(const float*)(p0 + 4);
                    const float v10 = *(const float*)(p1);
                    const float v11 = *(const float*)(p1 + 4);
                    o.w = (fmaf(MW.w, v01, v00) + MH.w * fmaf(MW.w, v11, v10)) * INV.w;
                }

                store_out(o, &out4[it * ACT + tid]);   // coalesced, nt
            }
        }
    }
}

extern "C" void kernel_launch(void* const* d_in, const int* in_sizes, int n_in,
                              void* d_out, int out_size, void* d_ws, size_t ws_size,
                              hipStream_t stream) {
    const float* tensor = (const float*)d_in[0];   // [8,1024,14,14] f32
    const float* roi    = (const float*)d_in[1];   // [512,5] f32
    float* out = (float*)d_out;                    // [512,1024,14,14] f32

    const int blocks = (out_size / (CPB * PER_CH));  // 512 * 32 = 16,384
    roi_pool_kernel<<<blocks, 256, 0, stream>>>(tensor, roi, out);
}

// Round 7
// 664.702 us; speedup vs baseline: 1.0589x; 1.0589x over previous
//
#include <hip/hip_runtime.h>

// ROI adaptive average pooling — R9: 4-PASS INSTRUMENTED OPTIMIZATION PROBE.
// B=8, C=1024, HW=14, N=512, FS=14, SCALE=1/16.
//
// R8 counters (first direct observation of the kernel): per-pass ~98us vs
// 65us write floor; store stream 4.34 TB/s vs fill's 6.2 on identical bytes;
// SQ_LDS_BANK_CONFLICT = 8.1M cycles/pass (contiguous-quad gather = stride-4
// lanes = 8-bank aliasing, reintroduced in R5/R6 for the float4 store);
// FETCH tiny -> no write-allocate RMW; VALUBusy 29%, Occ 45%.
//
// R9 fixes under test (REP=4 kept so the kernel stays visible in top-5):
//  1. Stride-49 gather mapping (thread owns q,q+49,q+98,q+147): lane
//     addresses stride-1 -> conflict-free. Stores become 4 coalesced plain
//     dwords.
//  2. Plain stores (drop nt): restore L2 write buffering (fill-path drains
//     at 6.2 TB/s through L2).
//  3. Geometry in registers (no LDS tables): LDS 29.2->25.1 KB -> 6
//     blocks/CU; one barrier removed; geometry VALU hides GLL latency.
// Readout pre-committed: conflicts <3e6; if per-pass -> 75-85us the fixes
// are real; if ~98us unchanged -> structural, revert + roofline next round.

#define FS_      14
#define PER_CH   196               // 14*14
#define C_       1024
#define CPB      32                // channels per block
#define QPC      49                // positions per thread-stride (196/4)
#define NSTAGE4  (CPB * PER_CH / 4)  // 1568 float4 to stage
#define ACT      245               // active compute threads = 5*49
#define REP      4
#define ROTS     205u              // odd -> bijection mod 512

#if defined(__has_builtin)
# if __has_builtin(__builtin_amdgcn_global_load_lds)
#  define USE_GLL 1
# endif
#endif

__global__ __launch_bounds__(256) void roi_pool_kernel(
    const float* __restrict__ tensor,
    const float* __restrict__ roi,
    float* __restrict__ out)
{
    __shared__ float s_plane[CPB * PER_CH + 4];   // 25,104 B (+4 zeroed pad)

    const unsigned bx = blockIdx.x;
    const unsigned n0 = bx >> 5;            // base ROI index
    const unsigned c0 = (bx & 31u) * CPB;   // first channel of this block

    const unsigned tid = threadIdx.x;
    const unsigned tc  = tid / QPC;         // 0..5 (5 = inactive spares)
    const unsigned q   = tid - tc * QPC;

    // Zero the overread pad ONCE (staging writes bytes [0,25088) only;
    // paired reads may touch +4B past the last plane; 0*pad must be 0).
    if (tid < 4u) s_plane[CPB * PER_CH + tid] = 0.0f;

    for (unsigned rep = 0; rep < REP; ++rep) {
        const unsigned n = (n0 + rep * ROTS) & 511u;   // this pass's ROI

        // ROI row [batch_idx, x1, y1, x2, y2] (uniform -> scalar).
        const float* r = roi + (size_t)n * 5;
        const int fm = (int)r[0];
        const int x1 = max((int)floorf(r[1] * 0.0625f), 0);
        const int y1 = max((int)floorf(r[2] * 0.0625f), 0);
        const int x2 = min((int)ceilf(r[3] * 0.0625f), FS_);
        const int y2 = min((int)ceilf(r[4] * 0.0625f), FS_);
        const unsigned Lh = (unsigned)(x2 - x1);   // 1..14 guaranteed
        const unsigned Lw = (unsigned)(y2 - y1);

        // Previous pass's gathers must be done before restaging s_plane.
        __syncthreads();

        // ---- Stage the 32 contiguous input planes of batch fm (async).
        const float4* __restrict__ src4 =
            (const float4*)(tensor + ((size_t)fm * C_ + c0) * PER_CH);
        float4* __restrict__ dst4 = (float4*)s_plane;
#pragma unroll
        for (unsigned k = 0; k < 7; ++k) {
            unsigned fi = k * 256u + tid;
            if (fi < NSTAGE4) {
#if defined(USE_GLL)
                __builtin_amdgcn_global_load_lds(
                    (const __attribute__((address_space(1))) void*)(src4 + fi),
                    (__attribute__((address_space(3))) void*)(dst4 + fi),
                    16, 0, 0);
#else
                dst4[fi] = src4[fi];
#endif
            }
        }

        // ---- Per-thread geometry in REGISTERS for positions q+49k
        // (overlaps the in-flight staging loads; no LDS tables, no extra
        // barrier).
        int   O0[4], O1[4];
        float MW[4], MH[4], INV[4];
        if (tid < ACT) {
#pragma unroll
            for (int k = 0; k < 4; ++k) {
                const unsigned p = q + QPC * (unsigned)k;   // 0..195
                const unsigned i = p / 14u;
                const unsigned j = p - i * 14u;
                const unsigned h0 = (i * Lh) / 14u;
                const unsigned h1 = ((i + 1u) * Lh + 13u) / 14u;
                const unsigned w0 = (j * Lw) / 14u;
                const unsigned w1 = ((j + 1u) * Lw + 13u) / 14u;
                const int dh = (int)(h1 - h0) - 1;     // 0 or 1
                const int dw = (int)(w1 - w0) - 1;     // 0 or 1
                const int a00 = (x1 + (int)h0) * FS_ + (y1 + (int)w0);
                O0[k] = a00 * 4;
                O1[k] = (a00 + FS_ * dh) * 4;
                MW[k] = (float)dw;
                MH[k] = (float)dh;
                const int cnt = (dh + 1) * (dw + 1);   // 1, 2, or 4
                INV[k] = (cnt == 1) ? 1.0f : ((cnt == 2) ? 0.5f : 0.25f);
            }
        }

        __syncthreads();   // staged planes visible

        // ---- Gather + plain coalesced dword stores (245 active threads).
        if (tid < ACT) {
            float* __restrict__ ob =
                out + ((size_t)n * C_ + c0) * PER_CH + q;

#pragma unroll
            for (unsigned it = 0; it < 7; ++it) {
                const unsigned cl = it * 5u + tc;  // local channel
                if (cl >= CPB) continue;           // trims last iteration
                const char* pb = (const char*)s_plane + cl * (PER_CH * 4);
                float* __restrict__ op = ob + cl * PER_CH;

#pragma unroll
                for (int k = 0; k < 4; ++k) {
                    const char* p0 = pb + O0[k];
                    const float v00 = *(const float*)(p0);
                    const float v01 = *(const float*)(p0 + 4); // ds_read2_b32
                    const char* p1 = pb + O1[k];
                    const float v10 = *(const float*)(p1);
                    const float v11 = *(const float*)(p1 + 4);
                    const float s = fmaf(MW[k], v01, v00)
                                  + MH[k] * fmaf(MW[k], v11, v10);
                    op[k * QPC] = s * INV[k];      // lanes stride-1, plain
                }
            }
        }
    }
}

extern "C" void kernel_launch(void* const* d_in, const int* in_sizes, int n_in,
                              void* d_out, int out_size, void* d_ws, size_t ws_size,
                              hipStream_t stream) {
    const float* tensor = (const float*)d_in[0];   // [8,1024,14,14] f32
    const float* roi    = (const float*)d_in[1];   // [512,5] f32
    float* out = (float*)d_out;                    // [512,1024,14,14] f32

    const int blocks = (out_size / (CPB * PER_CH));  // 512 * 32 = 16,384
    roi_pool_kernel<<<blocks, 256, 0, stream>>>(tensor, roi, out);
}

// Round 8
// 411.282 us; speedup vs baseline: 1.7113x; 1.6162x over previous
//
#include <hip/hip_runtime.h>

// ROI adaptive average pooling — R10: single-pass, wave-per-plane, CPB=16.
// B=8, C=1024, HW=14, N=512, FS=14, SCALE=1/16.
//
// Counter-driven ladder (R8/R9 4-pass probes gave direct kernel rows):
//   R8: per-pass 98us; 8.1M conflict-cyc/pass (stride-4 quad gather);
//       store stream 4.34 TB/s; FETCH tiny (no write-allocate RMW).
//   R9: stride-49 map + plain stores + reg geometry -> per-pass 81us,
//       conflicts -73%, stores 5.17 TB/s, Occ 50% (LDS granule caps blocks).
// Remaining drags: (a) waves mixing two planes offset 196 dwords (196%32=4)
// -> 3-way bank collisions between lane groups; (b) occupancy 50%.
//
// R10 structure:
//  - Thread p (<196) owns ONE position for ALL channels of the block; the
//    per-iteration gather has every lane in a wave reading the SAME plane
//    with monotone stride<=1 addresses (duplicates broadcast) -> zero bank
//    conflicts by construction. Stores stay stride-1 coalesced.
//  - CPB=16 planes/block (12.6 KB LDS, 32,768 blocks): same total staging
//    bytes, double residency cap -> occupancy toward 100%, deeper store
//    queue. Geometry = 5 scalar regs (O0,O1,MW,MH,INV).
//  - GLL width-16 staging, zeroed 4-float overread pad (paired read at the
//    last plane's last element touches +4B; 0*pad must be 0).
// Floor: 411 MB HBM write ~= 65us. Pre-committed: dur_us ~385-400, kernel
// hidden below the ~261us fills; >=410 -> fixed-overhead-pinned -> ROOFLINE.

#define FS_      14
#define PER_CH   196               // 14*14
#define C_       1024
#define CPB      16                // channels per block
#define NSTAGE4  (CPB * PER_CH / 4)  // 784 float4 to stage
#define ACT      PER_CH            // 196 active compute threads

#if defined(__has_builtin)
# if __has_builtin(__builtin_amdgcn_global_load_lds)
#  define USE_GLL 1
# endif
#endif

__global__ __launch_bounds__(256) void roi_pool_kernel(
    const float* __restrict__ tensor,
    const float* __restrict__ roi,
    float* __restrict__ out)
{
    __shared__ float s_plane[CPB * PER_CH + 4];   // 12,560 B (+4 zeroed pad)

    const unsigned bx = blockIdx.x;
    const unsigned n  = bx >> 6;            // ROI index (64 channel-groups)
    const unsigned c0 = (bx & 63u) * CPB;   // first channel of this block

    const unsigned tid = threadIdx.x;

    // ROI row [batch_idx, x1, y1, x2, y2] in 224-px coords (uniform -> scalar).
    const float* r = roi + (size_t)n * 5;
    const int fm = (int)r[0];
    const int x1 = max((int)floorf(r[1] * 0.0625f), 0);
    const int y1 = max((int)floorf(r[2] * 0.0625f), 0);
    const int x2 = min((int)ceilf(r[3] * 0.0625f), FS_);
    const int y2 = min((int)ceilf(r[4] * 0.0625f), FS_);
    const unsigned Lh = (unsigned)(x2 - x1);   // 1..14 guaranteed
    const unsigned Lw = (unsigned)(y2 - y1);

    // Zero the overread pad (staging writes bytes [0, CPB*784) only).
    if (tid < 4u) s_plane[CPB * PER_CH + tid] = 0.0f;

    // ---- Stage the 16 contiguous input planes of batch fm (async, 16B).
    const float4* __restrict__ src4 =
        (const float4*)(tensor + ((size_t)fm * C_ + c0) * PER_CH);
    float4* __restrict__ dst4 = (float4*)s_plane;
#pragma unroll
    for (unsigned k = 0; k < 4; ++k) {
        unsigned fi = k * 256u + tid;
        if (fi < NSTAGE4) {
#if defined(USE_GLL)
            __builtin_amdgcn_global_load_lds(
                (const __attribute__((address_space(1))) void*)(src4 + fi),
                (__attribute__((address_space(3))) void*)(dst4 + fi),
                16, 0, 0);
#else
            dst4[fi] = src4[fi];
#endif
        }
    }

    // ---- Per-thread geometry in registers (overlaps staging latency).
    int   O0 = 0, O1 = 0;
    float MW = 0.f, MH = 0.f, INV = 1.f;
    if (tid < ACT) {
        const unsigned p = tid;                 // this thread's position
        const unsigned i = p / 14u;
        const unsigned j = p - i * 14u;
        const unsigned h0 = (i * Lh) / 14u;
        const unsigned h1 = ((i + 1u) * Lh + 13u) / 14u;
        const unsigned w0 = (j * Lw) / 14u;
        const unsigned w1 = ((j + 1u) * Lw + 13u) / 14u;
        const int dh = (int)(h1 - h0) - 1;      // 0 or 1
        const int dw = (int)(w1 - w0) - 1;      // 0 or 1
        const int a00 = (x1 + (int)h0) * FS_ + (y1 + (int)w0);
        O0 = a00 * 4;
        O1 = (a00 + FS_ * dh) * 4;
        MW = (float)dw;
        MH = (float)dh;
        const int cnt = (dh + 1) * (dw + 1);    // 1, 2, or 4
        INV = (cnt == 1) ? 1.0f : ((cnt == 2) ? 0.5f : 0.25f);
    }

    __syncthreads();   // staged planes visible

    // ---- Gather + store: iteration cl reads ONE plane wave-uniformly.
    if (tid < ACT) {
        float* __restrict__ ob =
            out + ((size_t)n * C_ + c0) * PER_CH + tid;

#pragma unroll
        for (unsigned cl = 0; cl < CPB; ++cl) {
            const char* pb = (const char*)s_plane + cl * (PER_CH * 4);
            const char* p0 = pb + O0;
            const float v00 = *(const float*)(p0);
            const float v01 = *(const float*)(p0 + 4);   // ds_read2_b32 pair
            const char* p1 = pb + O1;
            const float v10 = *(const float*)(p1);
            const float v11 = *(const float*)(p1 + 4);
            const float s = fmaf(MW, v01, v00) + MH * fmaf(MW, v11, v10);
            ob[cl * PER_CH] = s * INV;           // lanes stride-1, coalesced
        }
    }
}

extern "C" void kernel_launch(void* const* d_in, const int* in_sizes, int n_in,
                              void* d_out, int out_size, void* d_ws, size_t ws_size,
                              hipStream_t stream) {
    const float* tensor = (const float*)d_in[0];   // [8,1024,14,14] f32
    const float* roi    = (const float*)d_in[1];   // [512,5] f32
    float* out = (float*)d_out;                    // [512,1024,14,14] f32

    const int blocks = (out_size / (CPB * PER_CH));  // 512 * 64 = 32,768
    roi_pool_kernel<<<blocks, 256, 0, stream>>>(tensor, roi, out);
}